// Round 7
// baseline (1922.990 us; speedup 1.0000x reference)
//
#include <hip/hip_runtime.h>
#include <hip/hip_bf16.h>
#include <math.h>

typedef __attribute__((ext_vector_type(8))) short bf16x8;
typedef __attribute__((ext_vector_type(8))) short short8v;
typedef __attribute__((ext_vector_type(4))) float f32x4;

namespace {
constexpr int N_ = 8192;
constexpr int M_ = 16384;
constexpr int D_ = 512;
constexpr int K_ = 10;
constexpr float EPS_ = 1e-8f;

constexpr int CAND = 16;        // candidates kept per row (rescored in fp32)
constexpr int CHUNKS = 4;       // M column chunks (bounds workspace: 64MB key buffer)
constexpr int CCOLS = M_ / CHUNKS;    // 4096
constexpr int PPR = 8;          // scan threads per row per chunk
constexpr int SLOTS = CHUNKS * PPR;   // 32 partial lists per row
constexpr int KSTR = 136;       // bf16 LDS key-tile stride: 128 cols + 8 pad (R5 bug: was 72 -> row overlap)
}

__device__ __forceinline__ float wredsum(float v) {
#pragma unroll
  for (int o = 32; o > 0; o >>= 1) v += __shfl_xor(v, o);
  return v;
}
__device__ __forceinline__ float wredmin(float v) {
#pragma unroll
  for (int o = 32; o > 0; o >>= 1) v = fminf(v, __shfl_xor(v, o));
  return v;
}
__device__ __forceinline__ float wredmax(float v) {
#pragma unroll
  for (int o = 32; o > 0; o >>= 1) v = fmaxf(v, __shfl_xor(v, o));
  return v;
}

// branchless sorted-ascending insert; all indices static (stays in VGPRs)
template <int KK>
__device__ __forceinline__ void ins_sorted(float (&L)[KK], int (&X)[KK], float v, int ix) {
  if (v >= L[KK - 1]) return;
#pragma unroll
  for (int j = KK - 1; j > 0; --j) {
    const bool sh = v < L[j - 1];
    const bool here = !sh && (v < L[j]);
    L[j] = sh ? L[j - 1] : (here ? v : L[j]);
    X[j] = sh ? X[j - 1] : (here ? ix : X[j]);
  }
  if (v < L[0]) { L[0] = v; X[0] = ix; }
}

__device__ __forceinline__ void gl_lds16(const void* g, void* l) {
  __builtin_amdgcn_global_load_lds(
      (const __attribute__((address_space(1))) unsigned int*)g,
      (__attribute__((address_space(3))) unsigned int*)l, 16, 0, 0);
}

__device__ __forceinline__ unsigned short f2bf(float v) {
  __hip_bfloat16 h = __float2bfloat16(v);
  return *reinterpret_cast<unsigned short*>(&h);
}

// ---------------- kernel 1: row norms + bf16 conversion (1 wave / row) ----------------
__global__ __launch_bounds__(256) void prep_k(const float* __restrict__ feat,
                                              const float* __restrict__ mem,
                                              float* __restrict__ x2, float* __restrict__ m2,
                                              unsigned short* __restrict__ fbf,
                                              unsigned short* __restrict__ mbf) {
  const int wv = threadIdx.x >> 6, lane = threadIdx.x & 63;
  const int w = blockIdx.x * 4 + wv;
  const float* src;
  float* dst;
  unsigned short* bdst;
  if (w < M_) {
    src = mem + (size_t)w * D_; dst = m2 + w; bdst = mbf + (size_t)w * D_;
  } else {
    const int r = w - M_;
    src = feat + (size_t)r * D_; dst = x2 + r; bdst = fbf + (size_t)r * D_;
  }
  const float4 a = *(const float4*)(src + lane * 8);
  const float4 b = *(const float4*)(src + lane * 8 + 4);
  float s = a.x * a.x + a.y * a.y + a.z * a.z + a.w * a.w +
            b.x * b.x + b.y * b.y + b.z * b.z + b.w * b.w;
  s = wredsum(s);
  if (lane == 0) *dst = s;
  short8v pk;
  pk[0] = (short)f2bf(a.x); pk[1] = (short)f2bf(a.y);
  pk[2] = (short)f2bf(a.z); pk[3] = (short)f2bf(a.w);
  pk[4] = (short)f2bf(b.x); pk[5] = (short)f2bf(b.y);
  pk[6] = (short)f2bf(b.z); pk[7] = (short)f2bf(b.w);
  *(short8v*)(bdst + lane * 8) = pk;
}

// ---------------- kernel 2: init global min/max ----------------
__global__ void init_k(unsigned int* __restrict__ dmm) {
  if (threadIdx.x == 0) {
    dmm[0] = 0x7f7fffffu;  // FLT_MAX bits (running min)
    dmm[1] = 0u;           // running max (all values > 0)
  }
}

// ---------------- kernel 3: m97-structure GEMM -> bf16 key tile (key = m2 - 2*cross) ----------------
// One M-chunk of 4096 cols. grid 2048 (64 q-blocks x 32 c-blocks, XCD-swizzled), block 256 (4 waves).
__global__ __launch_bounds__(256) void gemm_keys_k(
    const unsigned short* __restrict__ Abf, const unsigned short* __restrict__ Bbf,
    const float* __restrict__ m2c, unsigned short* __restrict__ Sc) {
  __shared__ char smraw[KSTR * 128 * 2];         // 34816 B: staging (32KB) and key tile overlap
  unsigned short* As = (unsigned short*)smraw;   // [128][64] bf16 linear
  unsigned short* Bs = As + 8192;                // [128][64]
  unsigned short* Ks = (unsigned short*)smraw;   // [128][KSTR] key tile (reuses staging)

  const int tid = threadIdx.x;
  const int wid = tid >> 6, lane = tid & 63;
  const int wr = wid >> 1, wc = wid & 1;
  const int lr = lane & 15, lg = lane >> 4;

  const int wg = blockIdx.x;
  const int swz = (wg & 7) * 256 + (wg >> 3);   // 2048 % 8 == 0: bijective XCD swizzle
  const int bq = swz >> 5, bc = swz & 31;
  const int row0 = bq * 128, col0 = bc * 128;

  const int srow = tid >> 3;          // staging row 0..31 per call
  const int sbyte = (tid & 7) * 16;
  const char* Ag = (const char*)Abf + (size_t)(row0 + srow) * 1024 + sbyte;
  const char* Bg = (const char*)Bbf + (size_t)(col0 + srow) * 1024 + sbyte;
  char* AsL = smraw + wid * 1024;
  char* BsL = smraw + 16384 + wid * 1024;

  f32x4 acc[4][4];
#pragma unroll
  for (int m = 0; m < 4; m++)
#pragma unroll
    for (int n = 0; n < 4; n++) acc[m][n] = (f32x4){0.f, 0.f, 0.f, 0.f};

  for (int kt = 0; kt < 8; ++kt) {
    __syncthreads();
#pragma unroll
    for (int it = 0; it < 4; ++it) {
      gl_lds16(Ag + kt * 128 + (size_t)it * 32768, AsL + it * 4096);
      gl_lds16(Bg + kt * 128 + (size_t)it * 32768, BsL + it * 4096);
    }
    __syncthreads();
#pragma unroll
    for (int kk = 0; kk < 2; ++kk) {
      bf16x8 af[4], bfg[4];
#pragma unroll
      for (int m = 0; m < 4; m++)
        af[m] = *(const bf16x8*)(As + (wr * 64 + m * 16 + lr) * 64 + kk * 32 + lg * 8);
#pragma unroll
      for (int n = 0; n < 4; n++)
        bfg[n] = *(const bf16x8*)(Bs + (wc * 64 + n * 16 + lr) * 64 + kk * 32 + lg * 8);
#pragma unroll
      for (int m = 0; m < 4; m++)
#pragma unroll
        for (int n = 0; n < 4; n++)
          acc[m][n] = __builtin_amdgcn_mfma_f32_16x16x32_bf16(af[m], bfg[n], acc[m][n], 0, 0, 0);
    }
  }
  // epilogue: key = m2 - 2*acc -> bf16 via LDS transpose-pack -> coalesced 16B stores
  __syncthreads();  // last MFMA frag reads done; LDS reusable
  float m2v[4];
#pragma unroll
  for (int n = 0; n < 4; n++) m2v[n] = m2c[col0 + wc * 64 + n * 16 + lr];
#pragma unroll
  for (int m = 0; m < 4; m++)
#pragma unroll
    for (int n = 0; n < 4; n++)
#pragma unroll
      for (int j = 0; j < 4; j++) {
        const float kf = fmaf(-2.0f, acc[m][n][j], m2v[n]);
        // C/D layout (verified r1/r2): row = (lane>>4)*4 + j, col = lane&15
        Ks[(wr * 64 + m * 16 + lg * 4 + j) * KSTR + (wc * 64 + n * 16 + lr)] = f2bf(kf);
      }
  __syncthreads();
#pragma unroll
  for (int q = 0; q < 8; ++q) {
    const int r = wid * 32 + q * 4 + lg;
    const short8v kv = *(const short8v*)(Ks + r * KSTR + lr * 8);
    *(short8v*)(Sc + (size_t)(row0 + r) * CCOLS + col0 + lr * 8) = kv;
  }
}

// ---------------- kernel 4: streaming scan of bf16 keys -> per-(row,slot) top-16 ----------------
// thread (row, p): pieces p, p+8, ... (16B interleave, coalesced 128B per 8 lanes)
__global__ __launch_bounds__(256) void scan_k(const unsigned short* __restrict__ Sc,
                                              float* __restrict__ pdist, int* __restrict__ pidx,
                                              int chunk) {
  const int g = blockIdx.x * 256 + threadIdx.x;
  const int row = g >> 3, p = g & 7;
  const unsigned short* Srow = Sc + (size_t)row * CCOLS;
  float L[CAND];
  int X[CAND];
#pragma unroll
  for (int i = 0; i < CAND; i++) { L[i] = 3.4e38f; X[i] = 0; }
  const int colbase = chunk * CCOLS;
  for (int i = 0; i < 64; ++i) {
    const int piece = i * 8 + p;
    const short8v v = *(const short8v*)(Srow + piece * 8);
    const int cb = colbase + piece * 8;
#pragma unroll
    for (int e = 0; e < 8; ++e) {
      const float f = __uint_as_float(((unsigned int)(unsigned short)v[e]) << 16);
      ins_sorted<CAND>(L, X, f, cb + e);
    }
  }
  const size_t base = ((size_t)row * SLOTS + chunk * PPR + p) * CAND;
#pragma unroll
  for (int k = 0; k < CAND; k++) { pdist[base + k] = L[k]; pidx[base + k] = X[k]; }
}

// ---------------- kernel 5: merge 32 partial lists per row -> top-16 candidate indices ----------------
__global__ __launch_bounds__(256) void merge16_k(const float* __restrict__ pdist,
                                                 const int* __restrict__ pidx,
                                                 int* __restrict__ cidx) {
  const int row = blockIdx.x * 256 + threadIdx.x;
  float L[CAND];
  int X[CAND];
#pragma unroll
  for (int i = 0; i < CAND; i++) { L[i] = 3.4e38f; X[i] = 0; }
  const size_t base = (size_t)row * SLOTS * CAND;
  for (int p4 = 0; p4 < SLOTS * CAND / 4; ++p4) {
    const float4 dv = *(const float4*)(pdist + base + p4 * 4);
    const int4 iv = *(const int4*)(pidx + base + p4 * 4);
    ins_sorted<CAND>(L, X, dv.x, iv.x);
    ins_sorted<CAND>(L, X, dv.y, iv.y);
    ins_sorted<CAND>(L, X, dv.z, iv.z);
    ins_sorted<CAND>(L, X, dv.w, iv.w);
  }
#pragma unroll
  for (int k = 0; k < CAND; k++) cidx[row * CAND + k] = X[k];
}

// ---------------- kernel 6: fp32 exact rescore of 16 candidates -> exact top-10 ----------------
__global__ __launch_bounds__(256) void rescore_k(
    const float* __restrict__ feat, const float* __restrict__ mem,
    const int* __restrict__ cidx, const float* __restrict__ x2, const float* __restrict__ m2,
    float* __restrict__ knn_out, int* __restrict__ nn1, float* __restrict__ dsArr,
    unsigned int* __restrict__ dmm) {
  __shared__ float rmn[4], rmx[4];
  const int wv = threadIdx.x >> 6, lane = threadIdx.x & 63;
  const int row = blockIdx.x * 4 + wv;
  const size_t fb = (size_t)row * D_;
  const float4 f0 = *(const float4*)(feat + fb + lane * 8);
  const float4 f1 = *(const float4*)(feat + fb + lane * 8 + 4);
  const float x2r = x2[row];
  float d16[CAND];
  int ci[CAND];
#pragma unroll
  for (int c = 0; c < CAND; ++c) {
    const int ix = cidx[row * CAND + c];
    ci[c] = ix;
    const size_t mb = (size_t)ix * D_;
    const float4 g0 = *(const float4*)(mem + mb + lane * 8);
    const float4 g1 = *(const float4*)(mem + mb + lane * 8 + 4);
    float s = f0.x * g0.x + f0.y * g0.y + f0.z * g0.z + f0.w * g0.w +
              f1.x * g1.x + f1.y * g1.y + f1.z * g1.z + f1.w * g1.w;
    s = wredsum(s);
    d16[c] = sqrtf(fmaxf(x2r + m2[ix] - 2.0f * s, 0.0f) + EPS_);
  }
  float L[K_];
  int X[K_];
#pragma unroll
  for (int i = 0; i < K_; i++) { L[i] = 3.4e38f; X[i] = 0; }
#pragma unroll
  for (int c = 0; c < CAND; ++c) ins_sorted<K_>(L, X, d16[c], ci[c]);
  float s10 = 0.f;
#pragma unroll
  for (int k = 0; k < K_; k++) s10 += L[k];
  const float mean = s10 * 0.1f;
  if (lane == 0) {
#pragma unroll
    for (int k = 0; k < K_; k++) knn_out[(size_t)row * K_ + k] = L[k];
    nn1[row] = X[0];
    dsArr[row] = mean;
    rmn[wv] = mean;
    rmx[wv] = mean;
  }
  __syncthreads();
  if (threadIdx.x == 0) {
    const float mn = fminf(fminf(rmn[0], rmn[1]), fminf(rmn[2], rmn[3]));
    const float mx = fmaxf(fmaxf(rmx[0], rmx[1]), fmaxf(rmx[2], rmx[3]));
    atomicMin(&dmm[0], __float_as_uint(mn));
    atomicMax(&dmm[1], __float_as_uint(mx));
  }
}

// ---------------- kernel 7: influence + noise_std ----------------
__global__ __launch_bounds__(256) void finalize_k(
    const float* __restrict__ feat, const float* __restrict__ mem,
    const float* __restrict__ knn, const int* __restrict__ nn1,
    const float* __restrict__ ds, const unsigned int* __restrict__ dmm,
    const float* __restrict__ iscale, const float* __restrict__ dscale,
    float* __restrict__ out_infl, float* __restrict__ out_noise) {
  const int wv = threadIdx.x >> 6, lane = threadIdx.x & 63;
  const int row = blockIdx.x * 4 + wv;
  const float d0 = knn[(size_t)row * K_];
  const float norm = d0 + EPS_;
  const int nb = nn1[row];
  const float dmin = __uint_as_float(dmm[0]);
  const float dmax = __uint_as_float(dmm[1]);
  const float dnorm = (ds[row] - dmin) / (dmax - dmin + EPS_);
  const float is = iscale[0], dsc = dscale[0];
  const size_t fb = (size_t)row * D_;
  const size_t nbase = (size_t)nb * D_;
  const float4 f0 = *(const float4*)(feat + fb + lane * 4);
  const float4 f1 = *(const float4*)(feat + fb + 256 + lane * 4);
  const float4 n0 = *(const float4*)(mem + nbase + lane * 4);
  const float4 n1 = *(const float4*)(mem + nbase + 256 + lane * 4);
  const float rn = 1.0f / norm;
  float inf[8];
  inf[0] = fabsf(f0.x - n0.x) * rn;
  inf[1] = fabsf(f0.y - n0.y) * rn;
  inf[2] = fabsf(f0.z - n0.z) * rn;
  inf[3] = fabsf(f0.w - n0.w) * rn;
  inf[4] = fabsf(f1.x - n1.x) * rn;
  inf[5] = fabsf(f1.y - n1.y) * rn;
  inf[6] = fabsf(f1.z - n1.z) * rn;
  inf[7] = fabsf(f1.w - n1.w) * rn;
  float mn = inf[0], mx = inf[0];
#pragma unroll
  for (int e = 1; e < 8; e++) {
    mn = fminf(mn, inf[e]);
    mx = fmaxf(mx, inf[e]);
  }
  mn = wredmin(mn);
  mx = wredmax(mx);
  const float inv = 1.0f / (mx - mn + EPS_);
  const float bd = dsc * dnorm;
  float nz[8];
#pragma unroll
  for (int e = 0; e < 8; e++) {
    const float innorm = (inf[e] - mn) * inv;
    const float comb = is * innorm + bd;
    nz[e] = 0.01f + 0.49f / (1.0f + expf(0.5f - comb));  // NOISE_MIN + range*sigmoid(comb-0.5)
  }
  *(float4*)(out_infl + fb + lane * 4) = make_float4(inf[0], inf[1], inf[2], inf[3]);
  *(float4*)(out_infl + fb + 256 + lane * 4) = make_float4(inf[4], inf[5], inf[6], inf[7]);
  *(float4*)(out_noise + fb + lane * 4) = make_float4(nz[0], nz[1], nz[2], nz[3]);
  *(float4*)(out_noise + fb + 256 + lane * 4) = make_float4(nz[4], nz[5], nz[6], nz[7]);
}

extern "C" void kernel_launch(void* const* d_in, const int* in_sizes, int n_in,
                              void* d_out, int out_size, void* d_ws, size_t ws_size,
                              hipStream_t stream) {
  const float* feat = (const float*)d_in[0];
  const float* mem = (const float*)d_in[1];
  const float* isc = (const float*)d_in[2];
  const float* dsc = (const float*)d_in[3];
  float* out = (float*)d_out;
  float* out_infl = out;
  float* out_noise = out + (size_t)N_ * D_;
  float* out_knn = out + (size_t)2 * N_ * D_;

  char* ws = (char*)d_ws;
  float* m2 = (float*)(ws + 0);                        //    64 KB
  float* x2 = (float*)(ws + 65536);                    //    32 KB
  float* dsA = (float*)(ws + 98304);                   //    32 KB
  unsigned int* dmm = (unsigned int*)(ws + 131072);    //   256 B
  int* nn1 = (int*)(ws + 131328);                      //    32 KB
  int* cidx = (int*)(ws + 164096);                     //   512 KB
  unsigned short* fbf = (unsigned short*)(ws + 688384);        //  8 MB
  unsigned short* mbf = (unsigned short*)(ws + 9076992);       // 16 MB
  float* pdist = (float*)(ws + 25854208);                      // 16 MB (N*32*16 f32)
  int* pidx = (int*)(ws + 42631424);                           // 16 MB
  unsigned short* S = (unsigned short*)(ws + 59408640);        // 64 MB (N*4096 bf16)

  hipLaunchKernelGGL(prep_k, dim3((M_ + N_) / 4), dim3(256), 0, stream, feat, mem, x2, m2, fbf, mbf);
  hipLaunchKernelGGL(init_k, dim3(1), dim3(64), 0, stream, dmm);
  for (int c = 0; c < CHUNKS; ++c) {
    hipLaunchKernelGGL(gemm_keys_k, dim3((N_ / 128) * (CCOLS / 128)), dim3(256), 0, stream,
                       fbf, mbf + (size_t)c * CCOLS * D_, m2 + c * CCOLS, S);
    hipLaunchKernelGGL(scan_k, dim3(N_ * PPR / 256), dim3(256), 0, stream, S, pdist, pidx, c);
  }
  hipLaunchKernelGGL(merge16_k, dim3(N_ / 256), dim3(256), 0, stream, pdist, pidx, cidx);
  hipLaunchKernelGGL(rescore_k, dim3(N_ / 4), dim3(256), 0, stream,
                     feat, mem, cidx, x2, m2, out_knn, nn1, dsA, dmm);
  hipLaunchKernelGGL(finalize_k, dim3(N_ / 4), dim3(256), 0, stream,
                     feat, mem, out_knn, nn1, dsA, dmm, isc, dsc, out_infl, out_noise);
}

// Round 9
// 973.746 us; speedup vs baseline: 1.9748x; 1.9748x over previous
//
#include <hip/hip_runtime.h>
#include <hip/hip_bf16.h>
#include <math.h>

typedef __attribute__((ext_vector_type(8))) short bf16x8;
typedef __attribute__((ext_vector_type(8))) short short8v;
typedef __attribute__((ext_vector_type(4))) float f32x4;

namespace {
constexpr int N_ = 8192;
constexpr int M_ = 16384;
constexpr int D_ = 512;
constexpr int K_ = 10;
constexpr float EPS_ = 1e-8f;

constexpr int CAND = 16;        // candidates kept per row (rescored in fp32)
constexpr int CHUNKS = 4;       // M column chunks (bounds workspace: 64MB key buffer)
constexpr int CCOLS = M_ / CHUNKS;    // 4096
constexpr int SLOTS = CHUNKS;   // R8: one top-16 list per row per chunk (was 8 threads x 4 chunks)
constexpr int KSTR = 136;       // bf16 LDS key-tile stride: 128 cols + 8 pad (R5 bug: was 72 -> row overlap)
}

__device__ __forceinline__ float wredsum(float v) {
#pragma unroll
  for (int o = 32; o > 0; o >>= 1) v += __shfl_xor(v, o);
  return v;
}
__device__ __forceinline__ float wredmin(float v) {
#pragma unroll
  for (int o = 32; o > 0; o >>= 1) v = fminf(v, __shfl_xor(v, o));
  return v;
}
__device__ __forceinline__ float wredmax(float v) {
#pragma unroll
  for (int o = 32; o > 0; o >>= 1) v = fmaxf(v, __shfl_xor(v, o));
  return v;
}

// branchless sorted-ascending insert; all indices static (stays in VGPRs)
template <int KK>
__device__ __forceinline__ void ins_sorted(float (&L)[KK], int (&X)[KK], float v, int ix) {
  if (v >= L[KK - 1]) return;
#pragma unroll
  for (int j = KK - 1; j > 0; --j) {
    const bool sh = v < L[j - 1];
    const bool here = !sh && (v < L[j]);
    L[j] = sh ? L[j - 1] : (here ? v : L[j]);
    X[j] = sh ? X[j - 1] : (here ? ix : X[j]);
  }
  if (v < L[0]) { L[0] = v; X[0] = ix; }
}

__device__ __forceinline__ void gl_lds16(const void* g, void* l) {
  __builtin_amdgcn_global_load_lds(
      (const __attribute__((address_space(1))) unsigned int*)g,
      (__attribute__((address_space(3))) unsigned int*)l, 16, 0, 0);
}

__device__ __forceinline__ unsigned short f2bf(float v) {
  __hip_bfloat16 h = __float2bfloat16(v);
  return *reinterpret_cast<unsigned short*>(&h);
}

// ---------------- kernel 1: row norms + bf16 conversion (1 wave / row) ----------------
__global__ __launch_bounds__(256) void prep_k(const float* __restrict__ feat,
                                              const float* __restrict__ mem,
                                              float* __restrict__ x2, float* __restrict__ m2,
                                              unsigned short* __restrict__ fbf,
                                              unsigned short* __restrict__ mbf) {
  const int wv = threadIdx.x >> 6, lane = threadIdx.x & 63;
  const int w = blockIdx.x * 4 + wv;
  const float* src;
  float* dst;
  unsigned short* bdst;
  if (w < M_) {
    src = mem + (size_t)w * D_; dst = m2 + w; bdst = mbf + (size_t)w * D_;
  } else {
    const int r = w - M_;
    src = feat + (size_t)r * D_; dst = x2 + r; bdst = fbf + (size_t)r * D_;
  }
  const float4 a = *(const float4*)(src + lane * 8);
  const float4 b = *(const float4*)(src + lane * 8 + 4);
  float s = a.x * a.x + a.y * a.y + a.z * a.z + a.w * a.w +
            b.x * b.x + b.y * b.y + b.z * b.z + b.w * b.w;
  s = wredsum(s);
  if (lane == 0) *dst = s;
  short8v pk;
  pk[0] = (short)f2bf(a.x); pk[1] = (short)f2bf(a.y);
  pk[2] = (short)f2bf(a.z); pk[3] = (short)f2bf(a.w);
  pk[4] = (short)f2bf(b.x); pk[5] = (short)f2bf(b.y);
  pk[6] = (short)f2bf(b.z); pk[7] = (short)f2bf(b.w);
  *(short8v*)(bdst + lane * 8) = pk;
}

// ---------------- kernel 2: init global min/max ----------------
__global__ void init_k(unsigned int* __restrict__ dmm) {
  if (threadIdx.x == 0) {
    dmm[0] = 0x7f7fffffu;  // FLT_MAX bits (running min)
    dmm[1] = 0u;           // running max (all values > 0)
  }
}

// ---------------- kernel 3: m97-structure GEMM -> bf16 key tile (key = m2 - 2*cross) ----------------
// One M-chunk of 4096 cols. grid 2048 (64 q-blocks x 32 c-blocks, XCD-swizzled), block 256 (4 waves).
__global__ __launch_bounds__(256) void gemm_keys_k(
    const unsigned short* __restrict__ Abf, const unsigned short* __restrict__ Bbf,
    const float* __restrict__ m2c, unsigned short* __restrict__ Sc) {
  __shared__ char smraw[KSTR * 128 * 2];         // 34816 B: staging (32KB) and key tile overlap
  unsigned short* As = (unsigned short*)smraw;   // [128][64] bf16 linear
  unsigned short* Bs = As + 8192;                // [128][64]
  unsigned short* Ks = (unsigned short*)smraw;   // [128][KSTR] key tile (reuses staging)

  const int tid = threadIdx.x;
  const int wid = tid >> 6, lane = tid & 63;
  const int wr = wid >> 1, wc = wid & 1;
  const int lr = lane & 15, lg = lane >> 4;

  const int wg = blockIdx.x;
  const int swz = (wg & 7) * 256 + (wg >> 3);   // 2048 % 8 == 0: bijective XCD swizzle
  const int bq = swz >> 5, bc = swz & 31;
  const int row0 = bq * 128, col0 = bc * 128;

  const int srow = tid >> 3;          // staging row 0..31 per call
  const int sbyte = (tid & 7) * 16;
  const char* Ag = (const char*)Abf + (size_t)(row0 + srow) * 1024 + sbyte;
  const char* Bg = (const char*)Bbf + (size_t)(col0 + srow) * 1024 + sbyte;
  char* AsL = smraw + wid * 1024;
  char* BsL = smraw + 16384 + wid * 1024;

  f32x4 acc[4][4];
#pragma unroll
  for (int m = 0; m < 4; m++)
#pragma unroll
    for (int n = 0; n < 4; n++) acc[m][n] = (f32x4){0.f, 0.f, 0.f, 0.f};

  for (int kt = 0; kt < 8; ++kt) {
    __syncthreads();
#pragma unroll
    for (int it = 0; it < 4; ++it) {
      gl_lds16(Ag + kt * 128 + (size_t)it * 32768, AsL + it * 4096);
      gl_lds16(Bg + kt * 128 + (size_t)it * 32768, BsL + it * 4096);
    }
    __syncthreads();
#pragma unroll
    for (int kk = 0; kk < 2; ++kk) {
      bf16x8 af[4], bfg[4];
#pragma unroll
      for (int m = 0; m < 4; m++)
        af[m] = *(const bf16x8*)(As + (wr * 64 + m * 16 + lr) * 64 + kk * 32 + lg * 8);
#pragma unroll
      for (int n = 0; n < 4; n++)
        bfg[n] = *(const bf16x8*)(Bs + (wc * 64 + n * 16 + lr) * 64 + kk * 32 + lg * 8);
#pragma unroll
      for (int m = 0; m < 4; m++)
#pragma unroll
        for (int n = 0; n < 4; n++)
          acc[m][n] = __builtin_amdgcn_mfma_f32_16x16x32_bf16(af[m], bfg[n], acc[m][n], 0, 0, 0);
    }
  }
  // epilogue: key = m2 - 2*acc -> bf16 via LDS transpose-pack -> coalesced 16B stores
  __syncthreads();  // last MFMA frag reads done; LDS reusable
  float m2v[4];
#pragma unroll
  for (int n = 0; n < 4; n++) m2v[n] = m2c[col0 + wc * 64 + n * 16 + lr];
#pragma unroll
  for (int m = 0; m < 4; m++)
#pragma unroll
    for (int n = 0; n < 4; n++)
#pragma unroll
      for (int j = 0; j < 4; j++) {
        const float kf = fmaf(-2.0f, acc[m][n][j], m2v[n]);
        // C/D layout (verified r1/r2): row = (lane>>4)*4 + j, col = lane&15
        Ks[(wr * 64 + m * 16 + lg * 4 + j) * KSTR + (wc * 64 + n * 16 + lr)] = f2bf(kf);
      }
  __syncthreads();
#pragma unroll
  for (int q = 0; q < 8; ++q) {
    const int r = wid * 32 + q * 4 + lg;
    const short8v kv = *(const short8v*)(Ks + r * KSTR + lr * 8);
    *(short8v*)(Sc + (size_t)(row0 + r) * CCOLS + col0 + lr * 8) = kv;
  }
}

// ---------------- kernel 4: wave-per-row scan of bf16 keys -> top-16 per row per chunk ----------------
// R8 rewrite: block = 4 waves = 4 rows; lane scans 64 elems (8 coalesced short8v loads),
// local sorted top-16, then wave-exact top-16 via 16 min-extractions (all static indices).
__global__ __launch_bounds__(256) void scan_k(const unsigned short* __restrict__ Sc,
                                              float* __restrict__ pdist, int* __restrict__ pidx,
                                              int chunk) {
  const int wv = threadIdx.x >> 6, lane = threadIdx.x & 63;
  const int row = blockIdx.x * 4 + wv;
  const unsigned short* Srow = Sc + (size_t)row * CCOLS;
  float L[CAND];
  int X[CAND];
#pragma unroll
  for (int i = 0; i < CAND; i++) { L[i] = 3.4e38f; X[i] = 0; }
  const int colbase = chunk * CCOLS;
#pragma unroll
  for (int i = 0; i < 8; ++i) {
    const int p16 = i * 64 + lane;                       // 512 pieces of 8 bf16, lane-strided
    const short8v v = *(const short8v*)(Srow + p16 * 8);
    const int cb = colbase + p16 * 8;
#pragma unroll
    for (int e = 0; e < 8; ++e) {
      const float f = __uint_as_float(((unsigned int)(unsigned short)v[e]) << 16);
      ins_sorted<CAND>(L, X, f, cb + e);
    }
  }
  // wave merge: extract global top-16 of 64 lane-lists by repeated min-extraction
  float* pd = pdist + ((size_t)row * CHUNKS + chunk) * CAND;
  int* px = pidx + ((size_t)row * CHUNKS + chunk) * CAND;
#pragma unroll
  for (int k = 0; k < CAND; ++k) {
    const float h = L[0];
    const float mn = wredmin(h);
    const unsigned long long mask = __ballot(h == mn);
    const int src = (int)__builtin_ctzll(mask);          // lowest winning lane pops
    const int idx = __shfl(X[0], src);
    if (lane == 0) { pd[k] = mn; px[k] = idx; }
    if (lane == src) {
#pragma unroll
      for (int j = 0; j < CAND - 1; ++j) { L[j] = L[j + 1]; X[j] = X[j + 1]; }
      L[CAND - 1] = 3.4e38f;
    }
  }
}

// ---------------- kernel 5: merge 4 partial lists per row -> top-16 candidate indices ----------------
__global__ __launch_bounds__(256) void merge16_k(const float* __restrict__ pdist,
                                                 const int* __restrict__ pidx,
                                                 int* __restrict__ cidx) {
  const int row = blockIdx.x * 256 + threadIdx.x;
  float L[CAND];
  int X[CAND];
#pragma unroll
  for (int i = 0; i < CAND; i++) { L[i] = 3.4e38f; X[i] = 0; }
  const size_t base = (size_t)row * SLOTS * CAND;
  for (int p4 = 0; p4 < SLOTS * CAND / 4; ++p4) {
    const float4 dv = *(const float4*)(pdist + base + p4 * 4);
    const int4 iv = *(const int4*)(pidx + base + p4 * 4);
    ins_sorted<CAND>(L, X, dv.x, iv.x);
    ins_sorted<CAND>(L, X, dv.y, iv.y);
    ins_sorted<CAND>(L, X, dv.z, iv.z);
    ins_sorted<CAND>(L, X, dv.w, iv.w);
  }
#pragma unroll
  for (int k = 0; k < CAND; k++) cidx[row * CAND + k] = X[k];
}

// ---------------- kernel 6: fp32 exact rescore of 16 candidates -> exact top-10 ----------------
__global__ __launch_bounds__(256) void rescore_k(
    const float* __restrict__ feat, const float* __restrict__ mem,
    const int* __restrict__ cidx, const float* __restrict__ x2, const float* __restrict__ m2,
    float* __restrict__ knn_out, int* __restrict__ nn1, float* __restrict__ dsArr,
    unsigned int* __restrict__ dmm) {
  __shared__ float rmn[4], rmx[4];
  const int wv = threadIdx.x >> 6, lane = threadIdx.x & 63;
  const int row = blockIdx.x * 4 + wv;
  const size_t fb = (size_t)row * D_;
  const float4 f0 = *(const float4*)(feat + fb + lane * 8);
  const float4 f1 = *(const float4*)(feat + fb + lane * 8 + 4);
  const float x2r = x2[row];
  float d16[CAND];
  int ci[CAND];
#pragma unroll
  for (int c = 0; c < CAND; ++c) {
    const int ix = cidx[row * CAND + c];
    ci[c] = ix;
    const size_t mb = (size_t)ix * D_;
    const float4 g0 = *(const float4*)(mem + mb + lane * 8);
    const float4 g1 = *(const float4*)(mem + mb + lane * 8 + 4);
    float s = f0.x * g0.x + f0.y * g0.y + f0.z * g0.z + f0.w * g0.w +
              f1.x * g1.x + f1.y * g1.y + f1.z * g1.z + f1.w * g1.w;
    s = wredsum(s);
    d16[c] = sqrtf(fmaxf(x2r + m2[ix] - 2.0f * s, 0.0f) + EPS_);
  }
  float L[K_];
  int X[K_];
#pragma unroll
  for (int i = 0; i < K_; i++) { L[i] = 3.4e38f; X[i] = 0; }
#pragma unroll
  for (int c = 0; c < CAND; ++c) ins_sorted<K_>(L, X, d16[c], ci[c]);
  float s10 = 0.f;
#pragma unroll
  for (int k = 0; k < K_; k++) s10 += L[k];
  const float mean = s10 * 0.1f;
  if (lane == 0) {
#pragma unroll
    for (int k = 0; k < K_; k++) knn_out[(size_t)row * K_ + k] = L[k];
    nn1[row] = X[0];
    dsArr[row] = mean;
    rmn[wv] = mean;
    rmx[wv] = mean;
  }
  __syncthreads();
  if (threadIdx.x == 0) {
    const float mn = fminf(fminf(rmn[0], rmn[1]), fminf(rmn[2], rmn[3]));
    const float mx = fmaxf(fmaxf(rmx[0], rmx[1]), fmaxf(rmx[2], rmx[3]));
    atomicMin(&dmm[0], __float_as_uint(mn));
    atomicMax(&dmm[1], __float_as_uint(mx));
  }
}

// ---------------- kernel 7: influence + noise_std ----------------
__global__ __launch_bounds__(256) void finalize_k(
    const float* __restrict__ feat, const float* __restrict__ mem,
    const float* __restrict__ knn, const int* __restrict__ nn1,
    const float* __restrict__ ds, const unsigned int* __restrict__ dmm,
    const float* __restrict__ iscale, const float* __restrict__ dscale,
    float* __restrict__ out_infl, float* __restrict__ out_noise) {
  const int wv = threadIdx.x >> 6, lane = threadIdx.x & 63;
  const int row = blockIdx.x * 4 + wv;
  const float d0 = knn[(size_t)row * K_];
  const float norm = d0 + EPS_;
  const int nb = nn1[row];
  const float dmin = __uint_as_float(dmm[0]);
  const float dmax = __uint_as_float(dmm[1]);
  const float dnorm = (ds[row] - dmin) / (dmax - dmin + EPS_);
  const float is = iscale[0], dsc = dscale[0];
  const size_t fb = (size_t)row * D_;
  const size_t nbase = (size_t)nb * D_;
  const float4 f0 = *(const float4*)(feat + fb + lane * 4);
  const float4 f1 = *(const float4*)(feat + fb + 256 + lane * 4);
  const float4 n0 = *(const float4*)(mem + nbase + lane * 4);
  const float4 n1 = *(const float4*)(mem + nbase + 256 + lane * 4);
  const float rn = 1.0f / norm;
  float inf[8];
  inf[0] = fabsf(f0.x - n0.x) * rn;
  inf[1] = fabsf(f0.y - n0.y) * rn;
  inf[2] = fabsf(f0.z - n0.z) * rn;
  inf[3] = fabsf(f0.w - n0.w) * rn;
  inf[4] = fabsf(f1.x - n1.x) * rn;
  inf[5] = fabsf(f1.y - n1.y) * rn;
  inf[6] = fabsf(f1.z - n1.z) * rn;
  inf[7] = fabsf(f1.w - n1.w) * rn;
  float mn = inf[0], mx = inf[0];
#pragma unroll
  for (int e = 1; e < 8; e++) {
    mn = fminf(mn, inf[e]);
    mx = fmaxf(mx, inf[e]);
  }
  mn = wredmin(mn);
  mx = wredmax(mx);
  const float inv = 1.0f / (mx - mn + EPS_);
  const float bd = dsc * dnorm;
  float nz[8];
#pragma unroll
  for (int e = 0; e < 8; e++) {
    const float innorm = (inf[e] - mn) * inv;
    const float comb = is * innorm + bd;
    nz[e] = 0.01f + 0.49f / (1.0f + expf(0.5f - comb));  // NOISE_MIN + range*sigmoid(comb-0.5)
  }
  *(float4*)(out_infl + fb + lane * 4) = make_float4(inf[0], inf[1], inf[2], inf[3]);
  *(float4*)(out_infl + fb + 256 + lane * 4) = make_float4(inf[4], inf[5], inf[6], inf[7]);
  *(float4*)(out_noise + fb + lane * 4) = make_float4(nz[0], nz[1], nz[2], nz[3]);
  *(float4*)(out_noise + fb + 256 + lane * 4) = make_float4(nz[4], nz[5], nz[6], nz[7]);
}

extern "C" void kernel_launch(void* const* d_in, const int* in_sizes, int n_in,
                              void* d_out, int out_size, void* d_ws, size_t ws_size,
                              hipStream_t stream) {
  const float* feat = (const float*)d_in[0];
  const float* mem = (const float*)d_in[1];
  const float* isc = (const float*)d_in[2];
  const float* dsc = (const float*)d_in[3];
  float* out = (float*)d_out;
  float* out_infl = out;
  float* out_noise = out + (size_t)N_ * D_;
  float* out_knn = out + (size_t)2 * N_ * D_;

  char* ws = (char*)d_ws;
  float* m2 = (float*)(ws + 0);                        //    64 KB
  float* x2 = (float*)(ws + 65536);                    //    32 KB
  float* dsA = (float*)(ws + 98304);                   //    32 KB
  unsigned int* dmm = (unsigned int*)(ws + 131072);    //   256 B
  int* nn1 = (int*)(ws + 131328);                      //    32 KB
  int* cidx = (int*)(ws + 164096);                     //   512 KB
  unsigned short* fbf = (unsigned short*)(ws + 688384);        //  8 MB
  unsigned short* mbf = (unsigned short*)(ws + 9076992);       // 16 MB
  float* pdist = (float*)(ws + 25854208);                      // 2 MB (N*4*16 f32)
  int* pidx = (int*)(ws + 42631424);                           // 2 MB
  unsigned short* S = (unsigned short*)(ws + 59408640);        // 64 MB (N*4096 bf16)

  hipLaunchKernelGGL(prep_k, dim3((M_ + N_) / 4), dim3(256), 0, stream, feat, mem, x2, m2, fbf, mbf);
  hipLaunchKernelGGL(init_k, dim3(1), dim3(64), 0, stream, dmm);
  for (int c = 0; c < CHUNKS; ++c) {
    hipLaunchKernelGGL(gemm_keys_k, dim3((N_ / 128) * (CCOLS / 128)), dim3(256), 0, stream,
                       fbf, mbf + (size_t)c * CCOLS * D_, m2 + c * CCOLS, S);
    hipLaunchKernelGGL(scan_k, dim3(N_ / 4), dim3(256), 0, stream, S, pdist, pidx, c);
  }
  hipLaunchKernelGGL(merge16_k, dim3(N_ / 256), dim3(256), 0, stream, pdist, pidx, cidx);
  hipLaunchKernelGGL(rescore_k, dim3(N_ / 4), dim3(256), 0, stream,
                     feat, mem, cidx, x2, m2, out_knn, nn1, dsA, dmm);
  hipLaunchKernelGGL(finalize_k, dim3(N_ / 4), dim3(256), 0, stream,
                     feat, mem, out_knn, nn1, dsA, dmm, isc, dsc, out_infl, out_noise);
}

// Round 11
// 520.937 us; speedup vs baseline: 3.6914x; 1.8692x over previous
//
#include <hip/hip_runtime.h>
#include <hip/hip_bf16.h>
#include <math.h>

typedef __attribute__((ext_vector_type(8))) short bf16x8;
typedef __attribute__((ext_vector_type(8))) short short8v;
typedef __attribute__((ext_vector_type(4))) float f32x4;

namespace {
constexpr int N_ = 8192;
constexpr int M_ = 16384;
constexpr int D_ = 512;
constexpr int K_ = 10;
constexpr float EPS_ = 1e-8f;

constexpr int CAND = 16;        // candidates kept per row (rescored in fp32)
constexpr int CHUNKS = 4;       // M column chunks (bounds workspace: 64MB key buffer)
constexpr int CCOLS = M_ / CHUNKS;    // 4096 (12-bit local col fits the packed u32)
constexpr int KSTR = 136;       // bf16 LDS key-tile stride: 128 cols + 8 pad (R5 bug: was 72 -> row overlap)
}

__device__ __forceinline__ float wredsum(float v) {
#pragma unroll
  for (int o = 32; o > 0; o >>= 1) v += __shfl_xor(v, o);
  return v;
}
__device__ __forceinline__ float wredmin(float v) {
#pragma unroll
  for (int o = 32; o > 0; o >>= 1) v = fminf(v, __shfl_xor(v, o));
  return v;
}
__device__ __forceinline__ float wredmax(float v) {
#pragma unroll
  for (int o = 32; o > 0; o >>= 1) v = fmaxf(v, __shfl_xor(v, o));
  return v;
}
__device__ __forceinline__ unsigned int wredmin_u32(unsigned int v) {
#pragma unroll
  for (int o = 32; o > 0; o >>= 1) {
    const unsigned int t = (unsigned int)__shfl_xor((int)v, o);
    v = t < v ? t : v;
  }
  return v;
}

// branchless sorted-ascending insert, float key + int payload (rescore path)
template <int KK>
__device__ __forceinline__ void ins_sorted(float (&L)[KK], int (&X)[KK], float v, int ix) {
  if (v >= L[KK - 1]) return;
#pragma unroll
  for (int j = KK - 1; j > 0; --j) {
    const bool sh = v < L[j - 1];
    const bool here = !sh && (v < L[j]);
    L[j] = sh ? L[j - 1] : (here ? v : L[j]);
    X[j] = sh ? X[j - 1] : (here ? ix : X[j]);
  }
  if (v < L[0]) { L[0] = v; X[0] = ix; }
}

// branchless sorted-ascending insert, single packed u32 (key<<16 | col) — R10
template <int KK>
__device__ __forceinline__ void ins_u32(unsigned int (&L)[KK], unsigned int v) {
  if (v >= L[KK - 1]) return;
#pragma unroll
  for (int j = KK - 1; j > 0; --j) {
    const bool sh = v < L[j - 1];
    L[j] = sh ? L[j - 1] : ((v < L[j]) ? v : L[j]);
  }
  if (v < L[0]) L[0] = v;
}

__device__ __forceinline__ void gl_lds16(const void* g, void* l) {
  __builtin_amdgcn_global_load_lds(
      (const __attribute__((address_space(1))) unsigned int*)g,
      (__attribute__((address_space(3))) unsigned int*)l, 16, 0, 0);
}

__device__ __forceinline__ unsigned short f2bf(float v) {
  __hip_bfloat16 h = __float2bfloat16(v);
  return *reinterpret_cast<unsigned short*>(&h);
}

// ---------------- kernel 1: row norms + bf16 conversion (1 wave / row) ----------------
__global__ __launch_bounds__(256) void prep_k(const float* __restrict__ feat,
                                              const float* __restrict__ mem,
                                              float* __restrict__ x2, float* __restrict__ m2,
                                              unsigned short* __restrict__ fbf,
                                              unsigned short* __restrict__ mbf) {
  const int wv = threadIdx.x >> 6, lane = threadIdx.x & 63;
  const int w = blockIdx.x * 4 + wv;
  const float* src;
  float* dst;
  unsigned short* bdst;
  if (w < M_) {
    src = mem + (size_t)w * D_; dst = m2 + w; bdst = mbf + (size_t)w * D_;
  } else {
    const int r = w - M_;
    src = feat + (size_t)r * D_; dst = x2 + r; bdst = fbf + (size_t)r * D_;
  }
  const float4 a = *(const float4*)(src + lane * 8);
  const float4 b = *(const float4*)(src + lane * 8 + 4);
  float s = a.x * a.x + a.y * a.y + a.z * a.z + a.w * a.w +
            b.x * b.x + b.y * b.y + b.z * b.z + b.w * b.w;
  s = wredsum(s);
  if (lane == 0) *dst = s;
  short8v pk;
  pk[0] = (short)f2bf(a.x); pk[1] = (short)f2bf(a.y);
  pk[2] = (short)f2bf(a.z); pk[3] = (short)f2bf(a.w);
  pk[4] = (short)f2bf(b.x); pk[5] = (short)f2bf(b.y);
  pk[6] = (short)f2bf(b.z); pk[7] = (short)f2bf(b.w);
  *(short8v*)(bdst + lane * 8) = pk;
}

// ---------------- kernel 2: init global min/max ----------------
__global__ void init_k(unsigned int* __restrict__ dmm) {
  if (threadIdx.x == 0) {
    dmm[0] = 0x7f7fffffu;  // FLT_MAX bits (running min)
    dmm[1] = 0u;           // running max (all values > 0)
  }
}

// ---------------- kernel 3: m97-structure GEMM -> bf16 key tile (key = max(m2 - 2*cross, 0)) ----------------
// One M-chunk of 4096 cols. grid 2048 (64 q-blocks x 32 c-blocks, XCD-swizzled), block 256 (4 waves).
// R10: clamp key at 0 so bf16 bit pattern (uint16) order == numeric order for the scan.
__global__ __launch_bounds__(256) void gemm_keys_k(
    const unsigned short* __restrict__ Abf, const unsigned short* __restrict__ Bbf,
    const float* __restrict__ m2c, unsigned short* __restrict__ Sc) {
  __shared__ char smraw[KSTR * 128 * 2];         // 34816 B: staging (32KB) and key tile overlap
  unsigned short* As = (unsigned short*)smraw;   // [128][64] bf16 linear
  unsigned short* Bs = As + 8192;                // [128][64]
  unsigned short* Ks = (unsigned short*)smraw;   // [128][KSTR] key tile (reuses staging)

  const int tid = threadIdx.x;
  const int wid = tid >> 6, lane = tid & 63;
  const int wr = wid >> 1, wc = wid & 1;
  const int lr = lane & 15, lg = lane >> 4;

  const int wg = blockIdx.x;
  const int swz = (wg & 7) * 256 + (wg >> 3);   // 2048 % 8 == 0: bijective XCD swizzle
  const int bq = swz >> 5, bc = swz & 31;
  const int row0 = bq * 128, col0 = bc * 128;

  const int srow = tid >> 3;          // staging row 0..31 per call
  const int sbyte = (tid & 7) * 16;
  const char* Ag = (const char*)Abf + (size_t)(row0 + srow) * 1024 + sbyte;
  const char* Bg = (const char*)Bbf + (size_t)(col0 + srow) * 1024 + sbyte;
  char* AsL = smraw + wid * 1024;
  char* BsL = smraw + 16384 + wid * 1024;

  f32x4 acc[4][4];
#pragma unroll
  for (int m = 0; m < 4; m++)
#pragma unroll
    for (int n = 0; n < 4; n++) acc[m][n] = (f32x4){0.f, 0.f, 0.f, 0.f};

  for (int kt = 0; kt < 8; ++kt) {
    __syncthreads();
#pragma unroll
    for (int it = 0; it < 4; ++it) {
      gl_lds16(Ag + kt * 128 + (size_t)it * 32768, AsL + it * 4096);
      gl_lds16(Bg + kt * 128 + (size_t)it * 32768, BsL + it * 4096);
    }
    __syncthreads();
#pragma unroll
    for (int kk = 0; kk < 2; ++kk) {
      bf16x8 af[4], bfg[4];
#pragma unroll
      for (int m = 0; m < 4; m++)
        af[m] = *(const bf16x8*)(As + (wr * 64 + m * 16 + lr) * 64 + kk * 32 + lg * 8);
#pragma unroll
      for (int n = 0; n < 4; n++)
        bfg[n] = *(const bf16x8*)(Bs + (wc * 64 + n * 16 + lr) * 64 + kk * 32 + lg * 8);
#pragma unroll
      for (int m = 0; m < 4; m++)
#pragma unroll
        for (int n = 0; n < 4; n++)
          acc[m][n] = __builtin_amdgcn_mfma_f32_16x16x32_bf16(af[m], bfg[n], acc[m][n], 0, 0, 0);
    }
  }
  // epilogue: key = max(m2 - 2*acc, 0) -> bf16 via LDS transpose-pack -> coalesced 16B stores
  __syncthreads();  // last MFMA frag reads done; LDS reusable
  float m2v[4];
#pragma unroll
  for (int n = 0; n < 4; n++) m2v[n] = m2c[col0 + wc * 64 + n * 16 + lr];
#pragma unroll
  for (int m = 0; m < 4; m++)
#pragma unroll
    for (int n = 0; n < 4; n++)
#pragma unroll
      for (int j = 0; j < 4; j++) {
        const float kf = fmaxf(fmaf(-2.0f, acc[m][n][j], m2v[n]), 0.0f);
        // C/D layout (verified r1/r2): row = (lane>>4)*4 + j, col = lane&15
        Ks[(wr * 64 + m * 16 + lg * 4 + j) * KSTR + (wc * 64 + n * 16 + lr)] = f2bf(kf);
      }
  __syncthreads();
#pragma unroll
  for (int q = 0; q < 8; ++q) {
    const int r = wid * 32 + q * 4 + lg;
    const short8v kv = *(const short8v*)(Ks + r * KSTR + lr * 8);
    *(short8v*)(Sc + (size_t)(row0 + r) * CCOLS + col0 + lr * 8) = kv;
  }
}

// ---------------- kernel 4: wave-per-row threshold scan -> packed top-16 per row per chunk ----------------
// R10 rewrite. Pass 1: lane key-min over its 64 elems (branchless umin). T = 16th smallest of the
// 64 lane minima (>=16 lanes have min <= T => >=16 elements <= T => packed-top-16 all have key <= T:
// exact filter). Pass 2: only elements with key <= T (~25-35 per wave) enter the packed-u32 insert.
// Packed value = (key16 << 16) | local_col(12b): u32 order == (key, col) order == numpy tie-break.
__global__ __launch_bounds__(256) void scan_k(const unsigned short* __restrict__ Sc,
                                              unsigned int* __restrict__ pc, int chunk) {
  const int wv = threadIdx.x >> 6, lane = threadIdx.x & 63;
  const int row = blockIdx.x * 4 + wv;
  const unsigned short* Srow = Sc + (size_t)row * CCOLS;

  // pass 1: load all 64 keys (raw cached in 32 VGPRs), lane key-min
  short8v raw[8];
  unsigned int kmin = 0xFFFFFFFFu;
#pragma unroll
  for (int i = 0; i < 8; ++i) {
    raw[i] = *(const short8v*)(Srow + (i * 64 + lane) * 8);
#pragma unroll
    for (int e = 0; e < 8; ++e) {
      const unsigned int k = (unsigned int)(unsigned short)raw[i][e];
      kmin = k < kmin ? k : kmin;
    }
  }
  // T = 16th smallest of the 64 lane minima (scalar min-extraction, no lists)
  unsigned int h = kmin;
  unsigned int T = 0xFFFFFFFFu;
#pragma unroll
  for (int k = 0; k < CAND; ++k) {
    const unsigned int mn = wredmin_u32(h);
    if (k == CAND - 1) T = mn;  // wave-uniform
    const unsigned long long mask = __ballot(h == mn);
    const int src = (int)__builtin_ctzll(mask);
    if (lane == src) h = 0xFFFFFFFFu;
  }
  // pass 2: filtered insert of packed (key<<16)|col
  unsigned int L[CAND];
#pragma unroll
  for (int i = 0; i < CAND; ++i) L[i] = 0xFFFFFFFFu;
#pragma unroll
  for (int i = 0; i < 8; ++i) {
    const int cb = (i * 64 + lane) * 8;
#pragma unroll
    for (int e = 0; e < 8; ++e) {
      const unsigned int k = (unsigned int)(unsigned short)raw[i][e];
      if (k <= T) ins_u32<CAND>(L, (k << 16) | (unsigned int)(cb + e));
    }
  }
  // exact wave top-16 by packed order via 16 min-extractions
  unsigned int* pd = pc + ((size_t)row * CHUNKS + chunk) * CAND;
#pragma unroll
  for (int k = 0; k < CAND; ++k) {
    const unsigned int mn = wredmin_u32(L[0]);
    if (lane == 0) pd[k] = mn;
    const unsigned long long mask = __ballot(L[0] == mn);
    const int src = (int)__builtin_ctzll(mask);
    if (lane == src) {
#pragma unroll
      for (int j = 0; j < CAND - 1; ++j) L[j] = L[j + 1];
      L[CAND - 1] = 0xFFFFFFFFu;
    }
  }
}

// ---------------- kernel 5: merge 4 packed lists per row -> top-16 global candidate indices ----------------
// Rebuild (key<<16)|global_col (14b fits); chunks ascending => cross-chunk ties keep lowest index.
__global__ __launch_bounds__(256) void merge16_k(const unsigned int* __restrict__ pc,
                                                 int* __restrict__ cidx) {
  const int row = blockIdx.x * 256 + threadIdx.x;
  unsigned int L[CAND];
#pragma unroll
  for (int i = 0; i < CAND; i++) L[i] = 0xFFFFFFFFu;
  const unsigned int* base = pc + (size_t)row * CHUNKS * CAND;
  for (int c = 0; c < CHUNKS; ++c) {
#pragma unroll
    for (int q = 0; q < CAND / 4; ++q) {
      const uint4 v4 = *(const uint4*)(base + c * CAND + q * 4);
      const unsigned int cb = (unsigned int)(c * CCOLS);
      ins_u32<CAND>(L, (v4.x & 0xFFFF0000u) | (cb + (v4.x & 0xFFFu)));
      ins_u32<CAND>(L, (v4.y & 0xFFFF0000u) | (cb + (v4.y & 0xFFFu)));
      ins_u32<CAND>(L, (v4.z & 0xFFFF0000u) | (cb + (v4.z & 0xFFFu)));
      ins_u32<CAND>(L, (v4.w & 0xFFFF0000u) | (cb + (v4.w & 0xFFFu)));
    }
  }
#pragma unroll
  for (int k = 0; k < CAND; k++) cidx[row * CAND + k] = (int)(L[k] & 0xFFFFu);
}

// ---------------- kernel 6: fp32 exact rescore of 16 candidates -> exact top-10 ----------------
__global__ __launch_bounds__(256) void rescore_k(
    const float* __restrict__ feat, const float* __restrict__ mem,
    const int* __restrict__ cidx, const float* __restrict__ x2, const float* __restrict__ m2,
    float* __restrict__ knn_out, int* __restrict__ nn1, float* __restrict__ dsArr,
    unsigned int* __restrict__ dmm) {
  __shared__ float rmn[4], rmx[4];
  const int wv = threadIdx.x >> 6, lane = threadIdx.x & 63;
  const int row = blockIdx.x * 4 + wv;
  const size_t fb = (size_t)row * D_;
  const float4 f0 = *(const float4*)(feat + fb + lane * 8);
  const float4 f1 = *(const float4*)(feat + fb + lane * 8 + 4);
  const float x2r = x2[row];
  float d16[CAND];
  int ci[CAND];
#pragma unroll
  for (int c = 0; c < CAND; ++c) {
    const int ix = cidx[row * CAND + c];
    ci[c] = ix;
    const size_t mb = (size_t)ix * D_;
    const float4 g0 = *(const float4*)(mem + mb + lane * 8);
    const float4 g1 = *(const float4*)(mem + mb + lane * 8 + 4);
    float s = f0.x * g0.x + f0.y * g0.y + f0.z * g0.z + f0.w * g0.w +
              f1.x * g1.x + f1.y * g1.y + f1.z * g1.z + f1.w * g1.w;
    s = wredsum(s);
    d16[c] = sqrtf(fmaxf(x2r + m2[ix] - 2.0f * s, 0.0f) + EPS_);
  }
  float L[K_];
  int X[K_];
#pragma unroll
  for (int i = 0; i < K_; i++) { L[i] = 3.4e38f; X[i] = 0; }
#pragma unroll
  for (int c = 0; c < CAND; ++c) ins_sorted<K_>(L, X, d16[c], ci[c]);
  float s10 = 0.f;
#pragma unroll
  for (int k = 0; k < K_; k++) s10 += L[k];
  const float mean = s10 * 0.1f;
  if (lane == 0) {
#pragma unroll
    for (int k = 0; k < K_; k++) knn_out[(size_t)row * K_ + k] = L[k];
    nn1[row] = X[0];
    dsArr[row] = mean;
    rmn[wv] = mean;
    rmx[wv] = mean;
  }
  __syncthreads();
  if (threadIdx.x == 0) {
    const float mn = fminf(fminf(rmn[0], rmn[1]), fminf(rmn[2], rmn[3]));
    const float mx = fmaxf(fmaxf(rmx[0], rmx[1]), fmaxf(rmx[2], rmx[3]));
    atomicMin(&dmm[0], __float_as_uint(mn));
    atomicMax(&dmm[1], __float_as_uint(mx));
  }
}

// ---------------- kernel 7: influence + noise_std ----------------
__global__ __launch_bounds__(256) void finalize_k(
    const float* __restrict__ feat, const float* __restrict__ mem,
    const float* __restrict__ knn, const int* __restrict__ nn1,
    const float* __restrict__ ds, const unsigned int* __restrict__ dmm,
    const float* __restrict__ iscale, const float* __restrict__ dscale,
    float* __restrict__ out_infl, float* __restrict__ out_noise) {
  const int wv = threadIdx.x >> 6, lane = threadIdx.x & 63;
  const int row = blockIdx.x * 4 + wv;
  const float d0 = knn[(size_t)row * K_];
  const float norm = d0 + EPS_;
  const int nb = nn1[row];
  const float dmin = __uint_as_float(dmm[0]);
  const float dmax = __uint_as_float(dmm[1]);
  const float dnorm = (ds[row] - dmin) / (dmax - dmin + EPS_);
  const float is = iscale[0], dsc = dscale[0];
  const size_t fb = (size_t)row * D_;
  const size_t nbase = (size_t)nb * D_;
  const float4 f0 = *(const float4*)(feat + fb + lane * 4);
  const float4 f1 = *(const float4*)(feat + fb + 256 + lane * 4);
  const float4 n0 = *(const float4*)(mem + nbase + lane * 4);
  const float4 n1 = *(const float4*)(mem + nbase + 256 + lane * 4);
  const float rn = 1.0f / norm;
  float inf[8];
  inf[0] = fabsf(f0.x - n0.x) * rn;
  inf[1] = fabsf(f0.y - n0.y) * rn;
  inf[2] = fabsf(f0.z - n0.z) * rn;
  inf[3] = fabsf(f0.w - n0.w) * rn;
  inf[4] = fabsf(f1.x - n1.x) * rn;
  inf[5] = fabsf(f1.y - n1.y) * rn;
  inf[6] = fabsf(f1.z - n1.z) * rn;
  inf[7] = fabsf(f1.w - n1.w) * rn;
  float mn = inf[0], mx = inf[0];
#pragma unroll
  for (int e = 1; e < 8; e++) {
    mn = fminf(mn, inf[e]);
    mx = fmaxf(mx, inf[e]);
  }
  mn = wredmin(mn);
  mx = wredmax(mx);
  const float inv = 1.0f / (mx - mn + EPS_);
  const float bd = dsc * dnorm;
  float nz[8];
#pragma unroll
  for (int e = 0; e < 8; e++) {
    const float innorm = (inf[e] - mn) * inv;
    const float comb = is * innorm + bd;
    nz[e] = 0.01f + 0.49f / (1.0f + expf(0.5f - comb));  // NOISE_MIN + range*sigmoid(comb-0.5)
  }
  *(float4*)(out_infl + fb + lane * 4) = make_float4(inf[0], inf[1], inf[2], inf[3]);
  *(float4*)(out_infl + fb + 256 + lane * 4) = make_float4(inf[4], inf[5], inf[6], inf[7]);
  *(float4*)(out_noise + fb + lane * 4) = make_float4(nz[0], nz[1], nz[2], nz[3]);
  *(float4*)(out_noise + fb + 256 + lane * 4) = make_float4(nz[4], nz[5], nz[6], nz[7]);
}

extern "C" void kernel_launch(void* const* d_in, const int* in_sizes, int n_in,
                              void* d_out, int out_size, void* d_ws, size_t ws_size,
                              hipStream_t stream) {
  const float* feat = (const float*)d_in[0];
  const float* mem = (const float*)d_in[1];
  const float* isc = (const float*)d_in[2];
  const float* dsc = (const float*)d_in[3];
  float* out = (float*)d_out;
  float* out_infl = out;
  float* out_noise = out + (size_t)N_ * D_;
  float* out_knn = out + (size_t)2 * N_ * D_;

  char* ws = (char*)d_ws;
  float* m2 = (float*)(ws + 0);                        //    64 KB
  float* x2 = (float*)(ws + 65536);                    //    32 KB
  float* dsA = (float*)(ws + 98304);                   //    32 KB
  unsigned int* dmm = (unsigned int*)(ws + 131072);    //   256 B
  int* nn1 = (int*)(ws + 131328);                      //    32 KB
  int* cidx = (int*)(ws + 164096);                     //   512 KB
  unsigned short* fbf = (unsigned short*)(ws + 688384);        //  8 MB
  unsigned short* mbf = (unsigned short*)(ws + 9076992);       // 16 MB
  unsigned int* pc = (unsigned int*)(ws + 25854208);           //  2 MB (N*4*16 u32 packed)
  unsigned short* S = (unsigned short*)(ws + 59408640);        // 64 MB (N*4096 bf16)

  hipLaunchKernelGGL(prep_k, dim3((M_ + N_) / 4), dim3(256), 0, stream, feat, mem, x2, m2, fbf, mbf);
  hipLaunchKernelGGL(init_k, dim3(1), dim3(64), 0, stream, dmm);
  for (int c = 0; c < CHUNKS; ++c) {
    hipLaunchKernelGGL(gemm_keys_k, dim3((N_ / 128) * (CCOLS / 128)), dim3(256), 0, stream,
                       fbf, mbf + (size_t)c * CCOLS * D_, m2 + c * CCOLS, S);
    hipLaunchKernelGGL(scan_k, dim3(N_ / 4), dim3(256), 0, stream, S, pc, c);
  }
  hipLaunchKernelGGL(merge16_k, dim3(N_ / 256), dim3(256), 0, stream, pc, cidx);
  hipLaunchKernelGGL(rescore_k, dim3(N_ / 4), dim3(256), 0, stream,
                     feat, mem, cidx, x2, m2, out_knn, nn1, dsA, dmm);
  hipLaunchKernelGGL(finalize_k, dim3(N_ / 4), dim3(256), 0, stream,
                     feat, mem, out_knn, nn1, dsA, dmm, isc, dsc, out_infl, out_noise);
}